// Round 4
// baseline (284.897 us; speedup 1.0000x reference)
//
#include <hip/hip_runtime.h>
#include <hip/hip_bf16.h>

// CPSFMemcellAutoencoder: B=8, 256x256 input, N=16, S=128, M=32, T=131072.
// R24: (1) REVERT conv2s to R22 (43.0us measured; R23's B-from-global regressed to
// 49.4us: 8 per-lane VMEM loads/stage + VGPR 48->68 dropped occupancy 36->25.6%).
// (2) conv2n_fused was co-#1 at 48.6us with VALUBusy 14.9% -- latency-bound on 144
// scalar bounds-checked NCHW loads/thread. Fix: n-branch conv1 now writes a_nc
// channels-last padded f32 [8][258][264][16] (interior at (h+1,w+1); sprep zeroes
// row0/col0 border); conv2n loads 9 taps x 4 float4 (36 vector loads, no bounds)
// and uses a prepped wn[k][ci][co] weight table (contiguous s_loads).
// f32 throughout the n-branch; only FMA summation order changes (negligible vs
// the fp8 s-branch error dominating absmax).
// Workspace layout (~260 MB):
//   [0, 67108864)             a_s8  : fp8 [8b][8 cg16][65536 hw][16 ci]
//     REUSED: t64 at [0, 33554432)  : POS-MAJOR [16 pos][131072 tok][4] f32
//   dec1 at [67108864, 73400320)    : [8,3,256,256] f32
//   xpad at [73400320, 76768768)    : bf16 padded x (R21)
//   wbf  at [76800000, 76810240)    : bf16 conv1s weights [128][40] (R21)
//   wn   at [76810240, 76819456)    : f32 conv2n weights [9][16][16] (R24)
//   a_nc at [77594624, 112467968)   : f32 channels-last padded n-branch act (R24)
//   [134217728, 167772160)    t_star: [T,128] bf16 token-major
//   [201326592, ...)          REUSED: wt8 (147456 B conv2_s weights fp8)
//     REUSED: part at +201850880 (1024 x 5120 f32 partials)
//   [243269632, 260046848)    wmat  : [T,32] f32  (written by conv2n_fused)
//   [260046848, 260050944)    WtW / [260050944, 260067328) WtT / [260067328, ...) cvn

#define ALPHA_F 1e-6f
#define TTOT 131072

typedef __attribute__((ext_vector_type(8))) short bf16x8;
typedef __attribute__((ext_vector_type(4))) float f32x4;

__device__ __forceinline__ float silu_f(float x) {
    return x * __builtin_amdgcn_rcpf(1.f + __expf(-x));
}

__device__ __forceinline__ short f2bf(float f) {
    __hip_bfloat16 h = __float2bfloat16(f);
    union { __hip_bfloat16 b; short s; } u; u.b = h; return u.s;
}

__device__ __forceinline__ float bf2f(unsigned short s) {
    union { unsigned u; float f; } c; c.u = (unsigned)s << 16; return c.f;
}

__device__ __forceinline__ int pack_fp8x4(float a, float b, float c, float d) {
    int lo = __builtin_amdgcn_cvt_pk_fp8_f32(a, b, 0, false);
    return  __builtin_amdgcn_cvt_pk_fp8_f32(c, d, lo, true);
}

// ---------------- conv 3x3, Cin=3, stride 1, pad 1, + bias + silu (NCHW f32 out) ----------------
template<int CO>
__global__ __launch_bounds__(256) void conv1_silu(
    const float* __restrict__ x, const float* __restrict__ wgt,
    const float* __restrict__ bias, float* __restrict__ out)
{
    int idx = blockIdx.x * 256 + threadIdx.x;      // (b,h,w)
    int w = idx & 255, h = (idx >> 8) & 255, b = idx >> 16;
    const float* xb = x + (size_t)b * 3 * 65536;
    float in[27];
#pragma unroll
    for (int ci = 0; ci < 3; ci++)
#pragma unroll
        for (int ky = 0; ky < 3; ky++)
#pragma unroll
            for (int kx = 0; kx < 3; kx++) {
                int hh = h + ky - 1, ww = w + kx - 1;
                bool ok = ((unsigned)hh < 256u) && ((unsigned)ww < 256u);
                in[(ci * 3 + ky) * 3 + kx] = ok ? xb[(ci << 16) + (hh << 8) + ww] : 0.f;
            }
    float* ob = out + (size_t)b * CO * 65536 + (h << 8) + w;
#pragma unroll 4
    for (int co = 0; co < CO; co++) {
        float acc = bias[co];          // uniform index -> s_load
#pragma unroll
        for (int k = 0; k < 27; k++) acc += in[k] * wgt[co * 27 + k];
        ob[(size_t)co << 16] = silu_f(acc);
    }
}

// ---- R24: n-branch conv1 -> channels-last padded a_nc [8][258][264][16] f32, interior (h+1,w+1)
__global__ __launch_bounds__(256) void conv1n_silu(
    const float* __restrict__ x, const float* __restrict__ wgt,
    const float* __restrict__ bias, float* __restrict__ anc)
{
    int idx = blockIdx.x * 256 + threadIdx.x;      // (b,h,w)
    int w = idx & 255, h = (idx >> 8) & 255, b = idx >> 16;
    const float* xb = x + (size_t)b * 3 * 65536;
    float in[27];
#pragma unroll
    for (int ci = 0; ci < 3; ci++)
#pragma unroll
        for (int ky = 0; ky < 3; ky++)
#pragma unroll
            for (int kx = 0; kx < 3; kx++) {
                int hh = h + ky - 1, ww = w + kx - 1;
                bool ok = ((unsigned)hh < 256u) && ((unsigned)ww < 256u);
                in[(ci * 3 + ky) * 3 + kx] = ok ? xb[(ci << 16) + (hh << 8) + ww] : 0.f;
            }
    float o[16];
#pragma unroll
    for (int co = 0; co < 16; co++) {
        float acc = bias[co];
#pragma unroll
        for (int k = 0; k < 27; k++) acc += in[k] * wgt[co * 27 + k];
        o[co] = silu_f(acc);
    }
    float* ob = anc + (((size_t)b * 258 + (h + 1)) * 264 + (w + 1)) * 16;
#pragma unroll
    for (int j = 0; j < 4; j++) *(float4*)&ob[4 * j] = *(float4*)&o[4 * j];
}

// ---- R21/R24 prep: xpad bf16 [8*3][258][272]; wbf bf16 [128][40]; wn f32 [9][16][16];
//      a_nc border zeroing (row0 + col0 per batch plane)
#define XPAD_DW 842112     // 24 * 258 * 136 dwords
__global__ __launch_bounds__(256) void sprep_kern(
    const float* __restrict__ x, const float* __restrict__ w1,
    const float* __restrict__ w2n,
    unsigned* __restrict__ xpad, unsigned* __restrict__ wbf,
    float* __restrict__ wn, float* __restrict__ anc)
{
    if (blockIdx.x >= 3291) {                      // a_nc border zeroing: 261 blocks
        int zidx = (blockIdx.x - 3291) * 256 + threadIdx.x;   // < 66816 exactly
        int b = zidx / 8352, j = zidx % 8352;
        size_t off;
        if (j < 4224) {              // row 0: c in [0,264), ci in [0,16)
            int c = j >> 4, ci = j & 15;
            off = (((size_t)b * 258 + 0) * 264 + c) * 16 + ci;
        } else {                     // col 0: r in [0,258), ci in [0,16)
            int j2 = j - 4224;
            int r = j2 >> 4, ci = j2 & 15;
            off = (((size_t)b * 258 + r) * 264 + 0) * 16 + ci;
        }
        anc[off] = 0.f;
        return;
    }
    if (blockIdx.x == 3290) {
        int t = threadIdx.x;
        if (t < 128) {               // wbf: conv1s weights, bf16 fragment rows
            int co = t;
            unsigned short row[28];
#pragma unroll
            for (int k = 0; k < 27; k++) row[k] = (unsigned short)f2bf(w1[co * 27 + k]);
            row[27] = 0;
#pragma unroll
            for (int j = 0; j < 14; j++)
                wbf[co * 20 + j] = (unsigned)row[2 * j] | ((unsigned)row[2 * j + 1] << 16);
#pragma unroll
            for (int j = 14; j < 20; j++) wbf[co * 20 + j] = 0u;
        }
        // wn[k][ci][co] = w2n[(co*16+ci)*9+k], 2304 entries, 9 per thread
#pragma unroll
        for (int u = 0; u < 9; u++) {
            int i = t * 9 + u;
            int co = i & 15, ci = (i >> 4) & 15, k = i >> 8;
            wn[i] = w2n[(co * 16 + ci) * 9 + k];
        }
        return;
    }
    int d = blockIdx.x * 256 + threadIdx.x;        // dword index in xpad
    if (d >= XPAD_DW) return;
    int w2 = d % 136;                              // dword col 0..135
    int rr = d / 136;                              // (b*3+ci)*258 + hp
    int hp = rr % 258;
    int plane = rr / 258;                          // b*3+ci
    unsigned val = 0u;
    if (hp >= 1 && hp <= 256 && w2 >= 4 && w2 <= 131) {
        const float* src = x + (size_t)plane * 65536 + (size_t)(hp - 1) * 256 + (2 * w2 - 8);
        float2 f = *(const float2*)src;
        val = (unsigned)(unsigned short)f2bf(f.x) |
              ((unsigned)(unsigned short)f2bf(f.y) << 16);
    }
    xpad[d] = val;
}

// ------- s-branch conv1: MFMA GEMM, fp8 out, co-split (128px x 64co per block) -------
// R21: staging from padded bf16 xpad (no bounds checks, no cvt); weights direct from wbf.
#define C1K 40   // padded k-stride (shorts)
__global__ __launch_bounds__(256) void conv1s_mfma(
    const unsigned short* __restrict__ xpad, const unsigned short* __restrict__ wbf,
    const float* __restrict__ bias, char* __restrict__ out8)
{
    __shared__ __align__(16) short Ps[128 * C1K];  // [pixel][k] 10240 B
    int tid = threadIdx.x;
    int g = blockIdx.x;                 // 8192: b*1024 + hhalf*2 + cohalf
    int b = g >> 10, rem = g & 1023;
    int hh2 = rem >> 1;                 // 0..511
    int h = hh2 >> 1, w0 = (hh2 & 1) * 128;
    int coB = (rem & 1) * 64;           // block's global co base

    int lane = tid & 63, wave = tid >> 6;
    int coL = (wave & 1) * 32, pxH = (wave >> 1) * 64;   // wave = 32co x 64px
    int r16 = lane & 15, q = lane >> 4, koff = q * 8;

    // A fragments direct from global (L2-resident, 16B aligned rows) -- no LDS, no sync dep
    bf16x8 af[2];
#pragma unroll
    for (int mt = 0; mt < 2; mt++)
        af[mt] = *(const bf16x8*)&wbf[(coB + coL + mt * 16 + r16) * C1K + koff];

    if (tid < 128) {
        int wpix = w0 + tid;
        const unsigned short* p0 = xpad + ((size_t)(b * 3) * 258 + h) * 272 + 7 + wpix;
        unsigned v[27];
#pragma unroll
        for (int ci = 0; ci < 3; ci++) {
            const unsigned short* pc = p0 + ci * 70176;   // 258*272
#pragma unroll
            for (int ky = 0; ky < 3; ky++)
#pragma unroll
                for (int kx = 0; kx < 3; kx++)
                    v[ci * 9 + ky * 3 + kx] = pc[ky * 272 + kx];  // offset-immediate loads
        }
        unsigned dw[16];
#pragma unroll
        for (int i = 0; i < 13; i++) dw[i] = v[2 * i] | (v[2 * i + 1] << 16);
        dw[13] = v[26];
        dw[14] = 0u; dw[15] = 0u;
#pragma unroll
        for (int j = 0; j < 4; j++)
            *(float4*)&Ps[tid * C1K + j * 8] = *(float4*)&dw[j * 4];
    }
    __syncthreads();

    bf16x8 bfr[4];
#pragma unroll
    for (int nt = 0; nt < 4; nt++)
        bfr[nt] = *(bf16x8*)&Ps[(pxH + nt * 16 + r16) * C1K + koff];
    f32x4 acc[2][4];
#pragma unroll
    for (int mt = 0; mt < 2; mt++)
#pragma unroll
        for (int nt = 0; nt < 4; nt++) {
#pragma unroll
            for (int r = 0; r < 4; r++) acc[mt][nt][r] = 0.f;
            acc[mt][nt] = __builtin_amdgcn_mfma_f32_16x16x32_bf16(
                af[mt], bfr[nt], acc[mt][nt], 0, 0, 0);
        }

    int hwb = (h << 8) + w0 + pxH;
    int* ob4 = (int*)out8 + (size_t)b * 8 * 65536 * 4;
#pragma unroll
    for (int mt = 0; mt < 2; mt++) {
        int cb = coB + coL + mt * 16 + q * 4;
        float4 bv = *(const float4*)&bias[cb];
        int cg = (coB + coL + mt * 16) >> 4;
#pragma unroll
        for (int nt = 0; nt < 4; nt++) {
            int hw = hwb + nt * 16 + r16;
            int pk = pack_fp8x4(silu_f(acc[mt][nt][0] + bv.x),
                                silu_f(acc[mt][nt][1] + bv.y),
                                silu_f(acc[mt][nt][2] + bv.z),
                                silu_f(acc[mt][nt][3] + bv.w));
            ob4[((size_t)cg * 65536 + hw) * 4 + q] = pk;
        }
    }
}

// ---- weight prep: wt8 fp8 chunk-major [pos][c16=ci/16][co][e=ci%16] from W[co][ci][ky][kx] f32 ----
__global__ __launch_bounds__(256) void wprep_kern(
    const float* __restrict__ w, int* __restrict__ wt8)
{
    int d = blockIdx.x * 256 + threadIdx.x;        // dword index < 36864
    int pos = d >> 12;
    int rb = (d << 2) & 16383;
    int c16 = rb >> 11, co = (rb >> 4) & 127, e0 = rb & 15;
    float f[4];
#pragma unroll
    for (int j = 0; j < 4; j++) {
        int ci = c16 * 16 + e0 + j;
        f[j] = w[co * 1152 + ci * 9 + pos];
    }
    wt8[d] = pack_fp8x4(f[0], f[1], f[2], f[3]);
}

// ------------- conv2_s implicit GEMM (R22-proven): fp8 operands, K=64 stages -------------
// Double-buffered 1-barrier pipeline + LDS half-row XOR swizzle (off ^ (row&8)).
__global__ __launch_bounds__(256) void conv2s_mfma(
    const char* __restrict__ a8,    // fp8 [8b][8 cg16][65536][16]
    const char* __restrict__ wt8,   // fp8 [9][8 c16][128][16]
    const float* __restrict__ bias, __hip_bfloat16* __restrict__ out)  // [T][128] bf16
{
    __shared__ __align__(16) char As[2][4096];    // [buf][row=cA*64+tok][16B]
    __shared__ __align__(16) char Bs[2][8192];    // [buf][row=c16*128+co][16B]
    int tid = threadIdx.x;
    int g = blockIdx.x;                 // 2048: b*256 + h2*2 + half
    int b = g >> 8, h2 = (g >> 1) & 127, w2base = (g & 1) * 64;
    int lane = tid & 63, wave = tid >> 6;
    int mrow = lane & 15, q = lane >> 4;

    f32x4 acc[2][4];   // [nt][mt]
#pragma unroll
    for (int i = 0; i < 2; i++)
#pragma unroll
        for (int j = 0; j < 4; j++)
#pragma unroll
            for (int r = 0; r < 4; r++) acc[i][j][r] = 0.f;

    const float4* ab4 = (const float4*)a8 + (size_t)b * 8 * 65536;
    const float4* wb4 = (const float4*)wt8;
    int cA = tid >> 6, tokA = tid & 63;
    int sB0 = tid, sB1 = tid + 256;
    int swT = tid & 8;                       // write-side swizzle (row&8; rows are tid / tid+256)
    int offA = ((q & 1) * 8) ^ (mrow & 8);   // read-side swizzled in-row offset

    // y = 2*h2-1+ky is only invalid for h2==0, ky==0 (pos 0..2) -> contiguous pos range
    int ps = (h2 == 0) ? 3 : 0;
    int nst = (9 - ps) * 2;                  // stages: (pos,cc), cc inner; always even

#define C2S_LOAD(s, ra, rb0, rb1) do {                                      \
        int pos_ = ps + ((s) >> 1), cc_ = (s) & 1;                          \
        int ky_ = pos_ / 3, kx_ = pos_ - 3 * ky_;                           \
        int y_ = 2 * h2 - 1 + ky_;                                          \
        int x_ = 2 * (w2base + tokA) - 1 + kx_;                             \
        int pix_ = (y_ << 8) + (x_ & 255);                                  \
        ra = make_float4(0.f, 0.f, 0.f, 0.f);                               \
        if (x_ >= 0) ra = ab4[(size_t)(cc_ * 4 + cA) * 65536 + pix_];       \
        const float4* brow_ = wb4 + pos_ * 1024 + cc_ * 512;                \
        rb0 = brow_[sB0]; rb1 = brow_[sB1];                                 \
    } while (0)

#define C2S_STORE(bufi, ra, rb0, rb1) do {                                  \
        union { float4 v; long l[2]; } uA_, u0_, u1_;                       \
        uA_.v = ra; u0_.v = rb0; u1_.v = rb1;                               \
        *(long*)&As[bufi][tid * 16 + swT]       = uA_.l[0];                 \
        *(long*)&As[bufi][tid * 16 + (8 ^ swT)] = uA_.l[1];                 \
        *(long*)&Bs[bufi][sB0 * 16 + swT]       = u0_.l[0];                 \
        *(long*)&Bs[bufi][sB0 * 16 + (8 ^ swT)] = u0_.l[1];                 \
        *(long*)&Bs[bufi][sB1 * 16 + swT]       = u1_.l[0];                 \
        *(long*)&Bs[bufi][sB1 * 16 + (8 ^ swT)] = u1_.l[1];                 \
    } while (0)

    auto compute = [&](const char* Ab, const char* Bb) {
#pragma unroll
        for (int kc = 0; kc < 2; kc++) {
            int cl = kc * 2 + (q >> 1);
            long afr[4], bfr[2];
#pragma unroll
            for (int mt = 0; mt < 4; mt++)
                afr[mt] = *(const long*)&Ab[(cl * 64 + mt * 16 + mrow) * 16 + offA];
#pragma unroll
            for (int nt = 0; nt < 2; nt++)
                bfr[nt] = *(const long*)&Bb[(cl * 128 + wave * 32 + nt * 16 + mrow) * 16 + offA];
#pragma unroll
            for (int nt = 0; nt < 2; nt++)
#pragma unroll
                for (int mt = 0; mt < 4; mt++)
                    acc[nt][mt] = __builtin_amdgcn_mfma_f32_16x16x32_fp8_fp8(
                        afr[mt], bfr[nt], acc[nt][mt], 0, 0, 0);
        }
    };

    {   // prologue: stage 0 -> buf 0
        float4 ra, rb0, rb1;
        C2S_LOAD(0, ra, rb0, rb1);
        C2S_STORE(0, ra, rb0, rb1);
    }
    __syncthreads();

    for (int s = 0; s < nst; s += 2) {
        float4 na, nb0, nb1;
        // stage s (buf 0): prefetch s+1 (always exists: nst even), compute, store -> buf 1
        C2S_LOAD(s + 1, na, nb0, nb1);
        compute(As[0], Bs[0]);
        C2S_STORE(1, na, nb0, nb1);
        __syncthreads();
        // stage s+1 (buf 1): prefetch s+2 if any, compute, store -> buf 0
        bool more = (s + 2 < nst);
        if (more) C2S_LOAD(s + 2, na, nb0, nb1);
        compute(As[1], Bs[1]);
        if (more) C2S_STORE(0, na, nb0, nb1);
        __syncthreads();
    }
#undef C2S_LOAD
#undef C2S_STORE

    int rowg = q * 4;
    size_t tbase = (size_t)g * 64;
#pragma unroll
    for (int nt = 0; nt < 2; nt++) {
        int co = wave * 32 + nt * 16 + mrow;
        float bvs = bias[co];
#pragma unroll
        for (int mt = 0; mt < 4; mt++)
#pragma unroll
            for (int r = 0; r < 4; r++) {
                int m = mt * 16 + rowg + r;
                out[(tbase + m) * 128 + co] =
                    __float2bfloat16(silu_f(acc[nt][mt][r] + bvs));
            }
    }
}

// ------- n-branch conv2 (16->16, s2) FUSED with memcell softmax: writes wmat [T,32] -------
// R24: reads channels-last padded a_nc (9 taps x 4 float4, no bounds checks) and
// prepped wn[k][ci][co] weights (contiguous s_loads).
__global__ __launch_bounds__(256) void conv2n_fused(
    const float* __restrict__ anc, const float* __restrict__ wn,
    const float* __restrict__ bias, const float* __restrict__ ck,
    float* __restrict__ wout)
{
    int idx = blockIdx.x * 256 + threadIdx.x;      // token (b,h2,w2)
    int w2 = idx & 127, h2 = (idx >> 7) & 127, b = idx >> 14;
    const float* pb = anc + (((size_t)b * 258 + 2 * h2) * 264 + 2 * w2) * 16;
    float acc[16];
#pragma unroll
    for (int co = 0; co < 16; co++) acc[co] = bias[co];
#pragma unroll
    for (int ky = 0; ky < 3; ky++)
#pragma unroll
        for (int kx = 0; kx < 3; kx++) {
            int k = ky * 3 + kx;
            const float* tp = pb + (ky * 264 + kx) * 16;
            float tap[16];
#pragma unroll
            for (int j = 0; j < 4; j++)
                *(float4*)&tap[4 * j] = *(const float4*)&tp[4 * j];
            const float* wk = wn + k * 256;        // [ci][co] contiguous
#pragma unroll
            for (int ci = 0; ci < 16; ci++) {
                float tv = tap[ci];
#pragma unroll
                for (int co = 0; co < 16; co++)
                    acc[co] += tv * wk[ci * 16 + co];   // uniform -> s_load runs
            }
        }
    float zv[16];
#pragma unroll
    for (int co = 0; co < 16; co++) zv[co] = silu_f(acc[co]);
    float lg[32]; float mx = -1e30f;
#pragma unroll
    for (int m = 0; m < 32; m++) {
        float a = 0.f;
#pragma unroll
        for (int n = 0; n < 16; n++) a += zv[n] * ck[m * 16 + n];   // uniform -> s_load
        a *= 0.25f;
        lg[m] = a; mx = fmaxf(mx, a);
    }
    float s = 0.f;
#pragma unroll
    for (int m = 0; m < 32; m++) { lg[m] = __expf(lg[m] - mx); s += lg[m]; }
    float inv = 1.f / s;      // precise: softmax feeds everything downstream
    float4* wp = (float4*)(wout + (size_t)idx * 32);
#pragma unroll
    for (int m = 0; m < 8; m++)
        wp[m] = make_float4(lg[4 * m] * inv, lg[4 * m + 1] * inv,
                            lg[4 * m + 2] * inv, lg[4 * m + 3] * inv);
}

// ---------------- WtW/WtT partials: 1024 blocks x 128 tokens, no atomics ----------------
__global__ __launch_bounds__(256) void memcell_acc_kern(
    const float* __restrict__ wmat, const __hip_bfloat16* __restrict__ tstar,
    float* __restrict__ part)
{
    __shared__ float ws[64][32];     // 8 KB
    __shared__ float ts[64 * 128];   // 32 KB
    int tid = threadIdx.x;
    int sg = tid & 31, mg = tid >> 5;
    int mW = tid & 31, m2 = (tid >> 5) * 4;
    float accT[16], accW[4];
#pragma unroll
    for (int i = 0; i < 16; i++) accT[i] = 0.f;
#pragma unroll
    for (int i = 0; i < 4; i++) accW[i] = 0.f;

#pragma unroll 1
    for (int cc = 0; cc < 2; cc++) {
        int c = blockIdx.x * 2 + cc;
        size_t base = (size_t)c * 64;
        __syncthreads();
        {
            const float4* src = (const float4*)(wmat + base * 32);
            float4* dst = (float4*)&ws[0][0];
#pragma unroll
            for (int i = 0; i < 2; i++) dst[tid + 256 * i] = src[tid + 256 * i];
            const float4* src2 = (const float4*)(tstar + base * 128);
#pragma unroll
            for (int i = 0; i < 4; i++) {
                union { float4 v; unsigned short us[8]; } u;
                u.v = src2[tid + 256 * i];
                float* d = &ts[(tid + 256 * i) * 8];
                float4 lo = make_float4(bf2f(u.us[0]), bf2f(u.us[1]), bf2f(u.us[2]), bf2f(u.us[3]));
                float4 hi = make_float4(bf2f(u.us[4]), bf2f(u.us[5]), bf2f(u.us[6]), bf2f(u.us[7]));
                *(float4*)d = lo; *(float4*)(d + 4) = hi;
            }
        }
        __syncthreads();
        for (int t = 0; t < 64; t++) {
            float4 wv = *(const float4*)&ws[t][mg * 4];
            float4 sv = *(const float4*)&ts[t * 128 + sg * 4];
            accT[0]  += wv.x * sv.x; accT[1]  += wv.x * sv.y; accT[2]  += wv.x * sv.z; accT[3]  += wv.x * sv.w;
            accT[4]  += wv.y * sv.x; accT[5]  += wv.y * sv.y; accT[6]  += wv.y * sv.z; accT[7]  += wv.y * sv.w;
            accT[8]  += wv.z * sv.x; accT[9]  += wv.z * sv.y; accT[10] += wv.z * sv.z; accT[11] += wv.z * sv.w;
            accT[12] += wv.w * sv.x; accT[13] += wv.w * sv.y; accT[14] += wv.w * sv.z; accT[15] += wv.w * sv.w;
            float wa = ws[t][mW];
            float4 wb = *(const float4*)&ws[t][m2];
            accW[0] += wa * wb.x; accW[1] += wa * wb.y;
            accW[2] += wa * wb.z; accW[3] += wa * wb.w;
        }
    }
    float* pb = part + (size_t)blockIdx.x * 5120;
#pragma unroll
    for (int i = 0; i < 16; i++) pb[i * 256 + tid] = accT[i];
#pragma unroll
    for (int i = 0; i < 4; i++) pb[4096 + i * 256 + tid] = accW[i];
}

// ---------------- reduce 1024 partials -> WtT [32,128], WtW [32,32] ----------------
__global__ __launch_bounds__(256) void memcell_reduce_kern(
    const float* __restrict__ part, float* __restrict__ WtT, float* __restrict__ WtW)
{
    int gid = blockIdx.x * 256 + threadIdx.x;   // 81920
    int j = gid % 5120, seg = gid / 5120;
    const float* p = part + (size_t)seg * 64 * 5120 + j;
    float s = 0.f;
#pragma unroll 8
    for (int k = 0; k < 64; k++) s += p[(size_t)k * 5120];
    int i = j >> 8, t = j & 255;
    if (j < 4096) {
        int sg = t & 31, mg = t >> 5;
        atomicAdd(&WtT[(mg * 4 + (i >> 2)) * 128 + sg * 4 + (i & 3)], s);
    } else {
        int i2 = i - 16;
        int mW = t & 31, m2 = (t >> 5) * 4;
        atomicAdd(&WtW[mW * 32 + m2 + i2], s);
    }
}

// ------- cell_v_new = cell_v + ALPHA*(WtT - WtW @ cell_v)  [32,128] -------
__global__ __launch_bounds__(256) void cvnew_kern(
    const float* __restrict__ cv, const float* __restrict__ WtW,
    const float* __restrict__ WtT, float* __restrict__ cvn)
{
    int idx = blockIdx.x * 256 + threadIdx.x;   // 4096
    int s = idx & 127, m = idx >> 7;
    float g = WtT[idx];
#pragma unroll
    for (int j = 0; j < 32; j++) g -= WtW[m * 32 + j] * cv[j * 128 + s];
    cvn[idx] = cv[idx] + ALPHA_F * g;
}

// ------- E[m][pos*4+co] = sum_ci cvn[m][ci] * dw[ci][co][kh][kw] -------
__global__ __launch_bounds__(256) void emat_kern(
    const float* __restrict__ cvn, const float* __restrict__ dw, float* __restrict__ E)
{
    int idx = blockIdx.x * 256 + threadIdx.x;   // 2048
    int m = idx >> 6, j = idx & 63;
    int pos = j >> 2, co = j & 3;
    float s = 0.f;
    if (co < 3) {
        const float* cv = cvn + m * 128;        // uniform per 64-lane group -> s_loads
        for (int ci = 0; ci < 128; ci++)
            s += cv[ci] * dw[ci * 48 + co * 16 + pos];
    }
    E[idx] = s;
}

// ------- t64[pos][Tglobal][4] = (wmat[T,32] @ E[32,64]) pos-major (coalesced stores) -------
__global__ __launch_bounds__(256) void tread64_kern(
    const float* __restrict__ wmat, const float* __restrict__ E, float* __restrict__ t64)
{
    int t = blockIdx.x * 256 + threadIdx.x;
    float wv[32];
    const float4* wp = (const float4*)(wmat + (size_t)t * 32);
#pragma unroll
    for (int i = 0; i < 8; i++) {
        float4 v = wp[i];
        wv[4 * i] = v.x; wv[4 * i + 1] = v.y; wv[4 * i + 2] = v.z; wv[4 * i + 3] = v.w;
    }
    f32x4 acc[16];
#pragma unroll
    for (int i = 0; i < 16; i++)
#pragma unroll
        for (int r = 0; r < 4; r++) acc[i][r] = 0.f;
    const f32x4* E4 = (const f32x4*)E;
#pragma unroll 4
    for (int m = 0; m < 32; m++) {
        float wm = wv[m];
#pragma unroll
        for (int i = 0; i < 16; i++) {
            f32x4 e = E4[m * 16 + i];           // uniform -> s_load_dwordx4
#pragma unroll
            for (int r = 0; r < 4; r++) acc[i][r] += wm * e[r];
        }
    }
    f32x4* ob = (f32x4*)t64;
#pragma unroll
    for (int i = 0; i < 16; i++)
        ob[(size_t)i * TTOT + t] = acc[i];      // lane-consecutive 16B per pos-plane
}

// ------- decoder gather: dec1 = silu(sum of 4 taps from t64 + bias) -------
__global__ __launch_bounds__(256) void dec_gather_kern(
    const float* __restrict__ t64, const float* __restrict__ db, float* __restrict__ out)
{
    int g = blockIdx.x;                   // 512: b*64 + hb*8 + wb
    int wb = g & 7, hb = (g >> 3) & 7, b = g >> 6;
    int tx = threadIdx.x & 15, ty = threadIdx.x >> 4;
    int h2 = hb * 16 + ty, w2 = wb * 16 + tx;

    float mh[3], mw[3];
    int ihc[3], iwc[3];
#pragma unroll
    for (int a = 0; a < 3; a++) {
        int v = h2 - 1 + a;
        mh[a] = ((unsigned)v < 128u) ? 1.f : 0.f;
        ihc[a] = v < 0 ? 0 : (v > 127 ? 127 : v);
        v = w2 - 1 + a;
        mw[a] = ((unsigned)v < 128u) ? 1.f : 0.f;
        iwc[a] = v < 0 ? 0 : (v > 127 ? 127 : v);
    }
    float acc[2][2][3];
#pragma unroll
    for (int ph = 0; ph < 2; ph++)
#pragma unroll
        for (int pw = 0; pw < 2; pw++)
#pragma unroll
            for (int co = 0; co < 3; co++) acc[ph][pw][co] = db[co];

    const int RA[4] = {0, 1, 1, 2}, RP[4] = {0, 0, 1, 1}, RK[4] = {3, 1, 2, 0};
    size_t tokb = (size_t)b * 16384;
#pragma unroll
    for (int ri = 0; ri < 4; ri++)
#pragma unroll
        for (int cj = 0; cj < 4; cj++) {
            int a = RA[ri], c = RA[cj];
            float m = mh[a] * mw[c];
            size_t tok = tokb + (ihc[a] << 7) + iwc[c];
            int pos = RK[ri] * 4 + RK[cj];
            float4 v = *(const float4*)&t64[((size_t)pos * TTOT + tok) * 4];
            int ph = RP[ri], pw = RP[cj];
            acc[ph][pw][0] += m * v.x;
            acc[ph][pw][1] += m * v.y;
            acc[ph][pw][2] += m * v.z;
        }
    int h = 2 * h2, w = 2 * w2;
#pragma unroll
    for (int ph = 0; ph < 2; ph++)
#pragma unroll
        for (int co = 0; co < 3; co++) {
            float2 v = make_float2(silu_f(acc[ph][0][co]), silu_f(acc[ph][1][co]));
            *(float2*)&out[(size_t)b * 3 * 65536 + (size_t)co * 65536 + ((size_t)(h + ph) << 8) + w] = v;
        }
}

extern "C" void kernel_launch(void* const* d_in, const int* in_sizes, int n_in,
                              void* d_out, int out_size, void* d_ws, size_t ws_size,
                              hipStream_t stream)
{
    const float* x      = (const float*)d_in[0];
    const float* e0n_w1 = (const float*)d_in[1];
    const float* e0n_b1 = (const float*)d_in[2];
    const float* e0n_w2 = (const float*)d_in[3];
    const float* e0n_b2 = (const float*)d_in[4];
    const float* e0s_w1 = (const float*)d_in[5];
    const float* e0s_b1 = (const float*)d_in[6];
    const float* e0s_w2 = (const float*)d_in[7];
    const float* e0s_b2 = (const float*)d_in[8];
    const float* d0_dw  = (const float*)d_in[9];
    const float* d0_db  = (const float*)d_in[10];
    const float* d0_cw  = (const float*)d_in[11];
    const float* d0_cb  = (const float*)d_in[12];
    const float* cell_k = (const float*)d_in[13];
    const float* cell_v = (const float*)d_in[14];
    float* outp = (float*)d_out;

    char* ws = (char*)d_ws;
    char* a_s8             = ws;                              // 67 MB fp8
    __hip_bfloat16* t_star = (__hip_bfloat16*)(ws + 134217728);
    char* wt8     = (char*)(ws + 201326592);
    float* part   = (float*)(ws + 201850880);                 // 21 MB partials
    float* Emat   = (float*)(ws + 224000000);                 // 8 KB
    float* wmat   = (float*)(ws + 243269632);
    float* WtW    = (float*)(ws + 260046848);
    float* WtT    = (float*)(ws + 260050944);
    float* cvn    = (float*)(ws + 260067328);
    float* t64    = (float*)(ws);               // reuse a_s8 region (dead after conv2s)
    float* dec1   = (float*)(ws + 67108864);
    unsigned* xpad = (unsigned*)(ws + 73400320);              // R21: bf16 padded x, 3.37 MB
    unsigned* wbf  = (unsigned*)(ws + 76800000);              // R21: bf16 conv1s weights, 10 KB
    float* wn      = (float*)(ws + 76810240);                 // R24: conv2n weights [9][16][16]
    float* a_nc    = (float*)(ws + 77594624);                 // R24: channels-last n-act, 34.9 MB

    // prep: padded bf16 x + conv1s bf16 weights + conv2n [k][ci][co] weights + a_nc borders
    sprep_kern<<<3552, 256, 0, stream>>>(x, e0s_w1, e0n_w2, xpad, wbf, wn, a_nc);
    // n-branch encoder; conv2n writes wmat directly (softmax fused)
    conv1n_silu<<<2048, 256, 0, stream>>>(x, e0n_w1, e0n_b1, a_nc);
    conv2n_fused<<<512, 256, 0, stream>>>(a_nc, wn, e0n_b2, cell_k, wmat);
    // s-branch encoder: fp8 MFMA conv1 (co-split) -> fp8 MFMA implicit-GEMM conv2
    wprep_kern<<<144, 256, 0, stream>>>(e0s_w2, (int*)wt8);
    conv1s_mfma<<<8192, 256, 0, stream>>>((const unsigned short*)xpad,
                                          (const unsigned short*)wbf, e0s_b1, a_s8);
    conv2s_mfma<<<2048, 256, 0, stream>>>(a_s8, wt8, e0s_b2, t_star);
    // memcell
    hipMemsetAsync(WtW, 0, (1024 + 4096) * sizeof(float), stream);
    memcell_acc_kern<<<1024, 256, 0, stream>>>(wmat, t_star, part);
    memcell_reduce_kern<<<320, 256, 0, stream>>>(part, WtT, WtW);
    cvnew_kern<<<16, 256, 0, stream>>>(cell_v, WtW, WtT, cvn);
    // decoder: fold deconv weights through cvn, then gather from wmat-space (pos-major t64)
    emat_kern<<<8, 256, 0, stream>>>(cvn, d0_dw, Emat);
    tread64_kern<<<512, 256, 0, stream>>>(wmat, Emat, t64);
    dec_gather_kern<<<512, 256, 0, stream>>>(t64, d0_db, dec1);
    conv1_silu<3><<<2048, 256, 0, stream>>>(dec1, d0_cw, d0_cb, outp);
}

// Round 5
// 273.802 us; speedup vs baseline: 1.0405x; 1.0405x over previous
//
#include <hip/hip_runtime.h>
#include <hip/hip_bf16.h>

// CPSFMemcellAutoencoder: B=8, 256x256 input, N=16, S=128, M=32, T=131072.
// R25: conv2n_fused ILP fix. R24 post-mortem: VGPR_Count=28 -- the compiler
// register-minimized and SERIALIZED the 36 tap loads (ILP=1); occupancy 19% is a
// GRID cap (512 blocks = 2048 waves = 25% of 8192 slots), not a resource cap.
// Fix: load all 9 taps (36 x float4 = 144 VGPR) up front, then compute. VGPR
// budget to ~200 is free: grid already caps at 2 waves/SIMD, same as a 256-VGPR
// kernel. 36 outstanding loads/wave x 8 waves/CU hides the ~500cy round trip.
// Accumulation order identical to R24 -> absmax unchanged.
// Everything else identical to R24 (conv2s = R22-proven 43us version).
// Workspace layout (~260 MB):
//   [0, 67108864)             a_s8  : fp8 [8b][8 cg16][65536 hw][16 ci]
//     REUSED: t64 at [0, 33554432)  : POS-MAJOR [16 pos][131072 tok][4] f32
//   dec1 at [67108864, 73400320)    : [8,3,256,256] f32
//   xpad at [73400320, 76768768)    : bf16 padded x (R21)
//   wbf  at [76800000, 76810240)    : bf16 conv1s weights [128][40] (R21)
//   wn   at [76810240, 76819456)    : f32 conv2n weights [9][16][16] (R24)
//   a_nc at [77594624, 112467968)   : f32 channels-last padded n-branch act (R24)
//   [134217728, 167772160)    t_star: [T,128] bf16 token-major
//   [201326592, ...)          REUSED: wt8 (147456 B conv2_s weights fp8)
//     REUSED: part at +201850880 (1024 x 5120 f32 partials)
//   [243269632, 260046848)    wmat  : [T,32] f32  (written by conv2n_fused)
//   [260046848, 260050944)    WtW / [260050944, 260067328) WtT / [260067328, ...) cvn

#define ALPHA_F 1e-6f
#define TTOT 131072

typedef __attribute__((ext_vector_type(8))) short bf16x8;
typedef __attribute__((ext_vector_type(4))) float f32x4;

__device__ __forceinline__ float silu_f(float x) {
    return x * __builtin_amdgcn_rcpf(1.f + __expf(-x));
}

__device__ __forceinline__ short f2bf(float f) {
    __hip_bfloat16 h = __float2bfloat16(f);
    union { __hip_bfloat16 b; short s; } u; u.b = h; return u.s;
}

__device__ __forceinline__ float bf2f(unsigned short s) {
    union { unsigned u; float f; } c; c.u = (unsigned)s << 16; return c.f;
}

__device__ __forceinline__ int pack_fp8x4(float a, float b, float c, float d) {
    int lo = __builtin_amdgcn_cvt_pk_fp8_f32(a, b, 0, false);
    return  __builtin_amdgcn_cvt_pk_fp8_f32(c, d, lo, true);
}

// ---------------- conv 3x3, Cin=3, stride 1, pad 1, + bias + silu (NCHW f32 out) ----------------
template<int CO>
__global__ __launch_bounds__(256) void conv1_silu(
    const float* __restrict__ x, const float* __restrict__ wgt,
    const float* __restrict__ bias, float* __restrict__ out)
{
    int idx = blockIdx.x * 256 + threadIdx.x;      // (b,h,w)
    int w = idx & 255, h = (idx >> 8) & 255, b = idx >> 16;
    const float* xb = x + (size_t)b * 3 * 65536;
    float in[27];
#pragma unroll
    for (int ci = 0; ci < 3; ci++)
#pragma unroll
        for (int ky = 0; ky < 3; ky++)
#pragma unroll
            for (int kx = 0; kx < 3; kx++) {
                int hh = h + ky - 1, ww = w + kx - 1;
                bool ok = ((unsigned)hh < 256u) && ((unsigned)ww < 256u);
                in[(ci * 3 + ky) * 3 + kx] = ok ? xb[(ci << 16) + (hh << 8) + ww] : 0.f;
            }
    float* ob = out + (size_t)b * CO * 65536 + (h << 8) + w;
#pragma unroll 4
    for (int co = 0; co < CO; co++) {
        float acc = bias[co];          // uniform index -> s_load
#pragma unroll
        for (int k = 0; k < 27; k++) acc += in[k] * wgt[co * 27 + k];
        ob[(size_t)co << 16] = silu_f(acc);
    }
}

// ---- R24: n-branch conv1 -> channels-last padded a_nc [8][258][264][16] f32, interior (h+1,w+1)
__global__ __launch_bounds__(256) void conv1n_silu(
    const float* __restrict__ x, const float* __restrict__ wgt,
    const float* __restrict__ bias, float* __restrict__ anc)
{
    int idx = blockIdx.x * 256 + threadIdx.x;      // (b,h,w)
    int w = idx & 255, h = (idx >> 8) & 255, b = idx >> 16;
    const float* xb = x + (size_t)b * 3 * 65536;
    float in[27];
#pragma unroll
    for (int ci = 0; ci < 3; ci++)
#pragma unroll
        for (int ky = 0; ky < 3; ky++)
#pragma unroll
            for (int kx = 0; kx < 3; kx++) {
                int hh = h + ky - 1, ww = w + kx - 1;
                bool ok = ((unsigned)hh < 256u) && ((unsigned)ww < 256u);
                in[(ci * 3 + ky) * 3 + kx] = ok ? xb[(ci << 16) + (hh << 8) + ww] : 0.f;
            }
    float o[16];
#pragma unroll
    for (int co = 0; co < 16; co++) {
        float acc = bias[co];
#pragma unroll
        for (int k = 0; k < 27; k++) acc += in[k] * wgt[co * 27 + k];
        o[co] = silu_f(acc);
    }
    float* ob = anc + (((size_t)b * 258 + (h + 1)) * 264 + (w + 1)) * 16;
#pragma unroll
    for (int j = 0; j < 4; j++) *(float4*)&ob[4 * j] = *(float4*)&o[4 * j];
}

// ---- R21/R24 prep: xpad bf16 [8*3][258][272]; wbf bf16 [128][40]; wn f32 [9][16][16];
//      a_nc border zeroing (row0 + col0 per batch plane)
#define XPAD_DW 842112     // 24 * 258 * 136 dwords
__global__ __launch_bounds__(256) void sprep_kern(
    const float* __restrict__ x, const float* __restrict__ w1,
    const float* __restrict__ w2n,
    unsigned* __restrict__ xpad, unsigned* __restrict__ wbf,
    float* __restrict__ wn, float* __restrict__ anc)
{
    if (blockIdx.x >= 3291) {                      // a_nc border zeroing: 261 blocks
        int zidx = (blockIdx.x - 3291) * 256 + threadIdx.x;   // < 66816 exactly
        int b = zidx / 8352, j = zidx % 8352;
        size_t off;
        if (j < 4224) {              // row 0: c in [0,264), ci in [0,16)
            int c = j >> 4, ci = j & 15;
            off = (((size_t)b * 258 + 0) * 264 + c) * 16 + ci;
        } else {                     // col 0: r in [0,258), ci in [0,16)
            int j2 = j - 4224;
            int r = j2 >> 4, ci = j2 & 15;
            off = (((size_t)b * 258 + r) * 264 + 0) * 16 + ci;
        }
        anc[off] = 0.f;
        return;
    }
    if (blockIdx.x == 3290) {
        int t = threadIdx.x;
        if (t < 128) {               // wbf: conv1s weights, bf16 fragment rows
            int co = t;
            unsigned short row[28];
#pragma unroll
            for (int k = 0; k < 27; k++) row[k] = (unsigned short)f2bf(w1[co * 27 + k]);
            row[27] = 0;
#pragma unroll
            for (int j = 0; j < 14; j++)
                wbf[co * 20 + j] = (unsigned)row[2 * j] | ((unsigned)row[2 * j + 1] << 16);
#pragma unroll
            for (int j = 14; j < 20; j++) wbf[co * 20 + j] = 0u;
        }
        // wn[k][ci][co] = w2n[(co*16+ci)*9+k], 2304 entries, 9 per thread
#pragma unroll
        for (int u = 0; u < 9; u++) {
            int i = t * 9 + u;
            int co = i & 15, ci = (i >> 4) & 15, k = i >> 8;
            wn[i] = w2n[(co * 16 + ci) * 9 + k];
        }
        return;
    }
    int d = blockIdx.x * 256 + threadIdx.x;        // dword index in xpad
    if (d >= XPAD_DW) return;
    int w2 = d % 136;                              // dword col 0..135
    int rr = d / 136;                              // (b*3+ci)*258 + hp
    int hp = rr % 258;
    int plane = rr / 258;                          // b*3+ci
    unsigned val = 0u;
    if (hp >= 1 && hp <= 256 && w2 >= 4 && w2 <= 131) {
        const float* src = x + (size_t)plane * 65536 + (size_t)(hp - 1) * 256 + (2 * w2 - 8);
        float2 f = *(const float2*)src;
        val = (unsigned)(unsigned short)f2bf(f.x) |
              ((unsigned)(unsigned short)f2bf(f.y) << 16);
    }
    xpad[d] = val;
}

// ------- s-branch conv1: MFMA GEMM, fp8 out, co-split (128px x 64co per block) -------
// R21: staging from padded bf16 xpad (no bounds checks, no cvt); weights direct from wbf.
#define C1K 40   // padded k-stride (shorts)
__global__ __launch_bounds__(256) void conv1s_mfma(
    const unsigned short* __restrict__ xpad, const unsigned short* __restrict__ wbf,
    const float* __restrict__ bias, char* __restrict__ out8)
{
    __shared__ __align__(16) short Ps[128 * C1K];  // [pixel][k] 10240 B
    int tid = threadIdx.x;
    int g = blockIdx.x;                 // 8192: b*1024 + hhalf*2 + cohalf
    int b = g >> 10, rem = g & 1023;
    int hh2 = rem >> 1;                 // 0..511
    int h = hh2 >> 1, w0 = (hh2 & 1) * 128;
    int coB = (rem & 1) * 64;           // block's global co base

    int lane = tid & 63, wave = tid >> 6;
    int coL = (wave & 1) * 32, pxH = (wave >> 1) * 64;   // wave = 32co x 64px
    int r16 = lane & 15, q = lane >> 4, koff = q * 8;

    // A fragments direct from global (L2-resident, 16B aligned rows) -- no LDS, no sync dep
    bf16x8 af[2];
#pragma unroll
    for (int mt = 0; mt < 2; mt++)
        af[mt] = *(const bf16x8*)&wbf[(coB + coL + mt * 16 + r16) * C1K + koff];

    if (tid < 128) {
        int wpix = w0 + tid;
        const unsigned short* p0 = xpad + ((size_t)(b * 3) * 258 + h) * 272 + 7 + wpix;
        unsigned v[27];
#pragma unroll
        for (int ci = 0; ci < 3; ci++) {
            const unsigned short* pc = p0 + ci * 70176;   // 258*272
#pragma unroll
            for (int ky = 0; ky < 3; ky++)
#pragma unroll
                for (int kx = 0; kx < 3; kx++)
                    v[ci * 9 + ky * 3 + kx] = pc[ky * 272 + kx];  // offset-immediate loads
        }
        unsigned dw[16];
#pragma unroll
        for (int i = 0; i < 13; i++) dw[i] = v[2 * i] | (v[2 * i + 1] << 16);
        dw[13] = v[26];
        dw[14] = 0u; dw[15] = 0u;
#pragma unroll
        for (int j = 0; j < 4; j++)
            *(float4*)&Ps[tid * C1K + j * 8] = *(float4*)&dw[j * 4];
    }
    __syncthreads();

    bf16x8 bfr[4];
#pragma unroll
    for (int nt = 0; nt < 4; nt++)
        bfr[nt] = *(bf16x8*)&Ps[(pxH + nt * 16 + r16) * C1K + koff];
    f32x4 acc[2][4];
#pragma unroll
    for (int mt = 0; mt < 2; mt++)
#pragma unroll
        for (int nt = 0; nt < 4; nt++) {
#pragma unroll
            for (int r = 0; r < 4; r++) acc[mt][nt][r] = 0.f;
            acc[mt][nt] = __builtin_amdgcn_mfma_f32_16x16x32_bf16(
                af[mt], bfr[nt], acc[mt][nt], 0, 0, 0);
        }

    int hwb = (h << 8) + w0 + pxH;
    int* ob4 = (int*)out8 + (size_t)b * 8 * 65536 * 4;
#pragma unroll
    for (int mt = 0; mt < 2; mt++) {
        int cb = coB + coL + mt * 16 + q * 4;
        float4 bv = *(const float4*)&bias[cb];
        int cg = (coB + coL + mt * 16) >> 4;
#pragma unroll
        for (int nt = 0; nt < 4; nt++) {
            int hw = hwb + nt * 16 + r16;
            int pk = pack_fp8x4(silu_f(acc[mt][nt][0] + bv.x),
                                silu_f(acc[mt][nt][1] + bv.y),
                                silu_f(acc[mt][nt][2] + bv.z),
                                silu_f(acc[mt][nt][3] + bv.w));
            ob4[((size_t)cg * 65536 + hw) * 4 + q] = pk;
        }
    }
}

// ---- weight prep: wt8 fp8 chunk-major [pos][c16=ci/16][co][e=ci%16] from W[co][ci][ky][kx] f32 ----
__global__ __launch_bounds__(256) void wprep_kern(
    const float* __restrict__ w, int* __restrict__ wt8)
{
    int d = blockIdx.x * 256 + threadIdx.x;        // dword index < 36864
    int pos = d >> 12;
    int rb = (d << 2) & 16383;
    int c16 = rb >> 11, co = (rb >> 4) & 127, e0 = rb & 15;
    float f[4];
#pragma unroll
    for (int j = 0; j < 4; j++) {
        int ci = c16 * 16 + e0 + j;
        f[j] = w[co * 1152 + ci * 9 + pos];
    }
    wt8[d] = pack_fp8x4(f[0], f[1], f[2], f[3]);
}

// ------------- conv2_s implicit GEMM (R22-proven): fp8 operands, K=64 stages -------------
// Double-buffered 1-barrier pipeline + LDS half-row XOR swizzle (off ^ (row&8)).
__global__ __launch_bounds__(256) void conv2s_mfma(
    const char* __restrict__ a8,    // fp8 [8b][8 cg16][65536][16]
    const char* __restrict__ wt8,   // fp8 [9][8 c16][128][16]
    const float* __restrict__ bias, __hip_bfloat16* __restrict__ out)  // [T][128] bf16
{
    __shared__ __align__(16) char As[2][4096];    // [buf][row=cA*64+tok][16B]
    __shared__ __align__(16) char Bs[2][8192];    // [buf][row=c16*128+co][16B]
    int tid = threadIdx.x;
    int g = blockIdx.x;                 // 2048: b*256 + h2*2 + half
    int b = g >> 8, h2 = (g >> 1) & 127, w2base = (g & 1) * 64;
    int lane = tid & 63, wave = tid >> 6;
    int mrow = lane & 15, q = lane >> 4;

    f32x4 acc[2][4];   // [nt][mt]
#pragma unroll
    for (int i = 0; i < 2; i++)
#pragma unroll
        for (int j = 0; j < 4; j++)
#pragma unroll
            for (int r = 0; r < 4; r++) acc[i][j][r] = 0.f;

    const float4* ab4 = (const float4*)a8 + (size_t)b * 8 * 65536;
    const float4* wb4 = (const float4*)wt8;
    int cA = tid >> 6, tokA = tid & 63;
    int sB0 = tid, sB1 = tid + 256;
    int swT = tid & 8;                       // write-side swizzle (row&8; rows are tid / tid+256)
    int offA = ((q & 1) * 8) ^ (mrow & 8);   // read-side swizzled in-row offset

    // y = 2*h2-1+ky is only invalid for h2==0, ky==0 (pos 0..2) -> contiguous pos range
    int ps = (h2 == 0) ? 3 : 0;
    int nst = (9 - ps) * 2;                  // stages: (pos,cc), cc inner; always even

#define C2S_LOAD(s, ra, rb0, rb1) do {                                      \
        int pos_ = ps + ((s) >> 1), cc_ = (s) & 1;                          \
        int ky_ = pos_ / 3, kx_ = pos_ - 3 * ky_;                           \
        int y_ = 2 * h2 - 1 + ky_;                                          \
        int x_ = 2 * (w2base + tokA) - 1 + kx_;                             \
        int pix_ = (y_ << 8) + (x_ & 255);                                  \
        ra = make_float4(0.f, 0.f, 0.f, 0.f);                               \
        if (x_ >= 0) ra = ab4[(size_t)(cc_ * 4 + cA) * 65536 + pix_];       \
        const float4* brow_ = wb4 + pos_ * 1024 + cc_ * 512;                \
        rb0 = brow_[sB0]; rb1 = brow_[sB1];                                 \
    } while (0)

#define C2S_STORE(bufi, ra, rb0, rb1) do {                                  \
        union { float4 v; long l[2]; } uA_, u0_, u1_;                       \
        uA_.v = ra; u0_.v = rb0; u1_.v = rb1;                               \
        *(long*)&As[bufi][tid * 16 + swT]       = uA_.l[0];                 \
        *(long*)&As[bufi][tid * 16 + (8 ^ swT)] = uA_.l[1];                 \
        *(long*)&Bs[bufi][sB0 * 16 + swT]       = u0_.l[0];                 \
        *(long*)&Bs[bufi][sB0 * 16 + (8 ^ swT)] = u0_.l[1];                 \
        *(long*)&Bs[bufi][sB1 * 16 + swT]       = u1_.l[0];                 \
        *(long*)&Bs[bufi][sB1 * 16 + (8 ^ swT)] = u1_.l[1];                 \
    } while (0)

    auto compute = [&](const char* Ab, const char* Bb) {
#pragma unroll
        for (int kc = 0; kc < 2; kc++) {
            int cl = kc * 2 + (q >> 1);
            long afr[4], bfr[2];
#pragma unroll
            for (int mt = 0; mt < 4; mt++)
                afr[mt] = *(const long*)&Ab[(cl * 64 + mt * 16 + mrow) * 16 + offA];
#pragma unroll
            for (int nt = 0; nt < 2; nt++)
                bfr[nt] = *(const long*)&Bb[(cl * 128 + wave * 32 + nt * 16 + mrow) * 16 + offA];
#pragma unroll
            for (int nt = 0; nt < 2; nt++)
#pragma unroll
                for (int mt = 0; mt < 4; mt++)
                    acc[nt][mt] = __builtin_amdgcn_mfma_f32_16x16x32_fp8_fp8(
                        afr[mt], bfr[nt], acc[nt][mt], 0, 0, 0);
        }
    };

    {   // prologue: stage 0 -> buf 0
        float4 ra, rb0, rb1;
        C2S_LOAD(0, ra, rb0, rb1);
        C2S_STORE(0, ra, rb0, rb1);
    }
    __syncthreads();

    for (int s = 0; s < nst; s += 2) {
        float4 na, nb0, nb1;
        // stage s (buf 0): prefetch s+1 (always exists: nst even), compute, store -> buf 1
        C2S_LOAD(s + 1, na, nb0, nb1);
        compute(As[0], Bs[0]);
        C2S_STORE(1, na, nb0, nb1);
        __syncthreads();
        // stage s+1 (buf 1): prefetch s+2 if any, compute, store -> buf 0
        bool more = (s + 2 < nst);
        if (more) C2S_LOAD(s + 2, na, nb0, nb1);
        compute(As[1], Bs[1]);
        if (more) C2S_STORE(0, na, nb0, nb1);
        __syncthreads();
    }
#undef C2S_LOAD
#undef C2S_STORE

    int rowg = q * 4;
    size_t tbase = (size_t)g * 64;
#pragma unroll
    for (int nt = 0; nt < 2; nt++) {
        int co = wave * 32 + nt * 16 + mrow;
        float bvs = bias[co];
#pragma unroll
        for (int mt = 0; mt < 4; mt++)
#pragma unroll
            for (int r = 0; r < 4; r++) {
                int m = mt * 16 + rowg + r;
                out[(tbase + m) * 128 + co] =
                    __float2bfloat16(silu_f(acc[nt][mt][r] + bvs));
            }
    }
}

// ------- n-branch conv2 (16->16, s2) FUSED with memcell softmax: writes wmat [T,32] -------
// R25: all 9 taps loaded up-front into registers (36 outstanding float4 loads;
// grid caps occupancy at 2 waves/SIMD so the ~190 VGPRs are free).
__global__ __launch_bounds__(256) void conv2n_fused(
    const float* __restrict__ anc, const float* __restrict__ wn,
    const float* __restrict__ bias, const float* __restrict__ ck,
    float* __restrict__ wout)
{
    int idx = blockIdx.x * 256 + threadIdx.x;      // token (b,h2,w2)
    int w2 = idx & 127, h2 = (idx >> 7) & 127, b = idx >> 14;
    const float* pb = anc + (((size_t)b * 258 + 2 * h2) * 264 + 2 * w2) * 16;
    // ---- issue ALL 36 vector loads before any use (MLP needs the ILP) ----
    float4 tv[9][4];
#pragma unroll
    for (int ky = 0; ky < 3; ky++)
#pragma unroll
        for (int kx = 0; kx < 3; kx++) {
            const float* tp = pb + (ky * 264 + kx) * 16;
#pragma unroll
            for (int j = 0; j < 4; j++)
                tv[ky * 3 + kx][j] = *(const float4*)&tp[4 * j];
        }
    float acc[16];
#pragma unroll
    for (int co = 0; co < 16; co++) acc[co] = bias[co];
#pragma unroll
    for (int k = 0; k < 9; k++) {
        float tap[16];
#pragma unroll
        for (int j = 0; j < 4; j++) *(float4*)&tap[4 * j] = tv[k][j];
        const float* wk = wn + k * 256;        // [ci][co] contiguous
#pragma unroll
        for (int ci = 0; ci < 16; ci++) {
            float tvv = tap[ci];
#pragma unroll
            for (int co = 0; co < 16; co++)
                acc[co] += tvv * wk[ci * 16 + co];   // uniform -> s_load runs
        }
    }
    float zv[16];
#pragma unroll
    for (int co = 0; co < 16; co++) zv[co] = silu_f(acc[co]);
    float lg[32]; float mx = -1e30f;
#pragma unroll
    for (int m = 0; m < 32; m++) {
        float a = 0.f;
#pragma unroll
        for (int n = 0; n < 16; n++) a += zv[n] * ck[m * 16 + n];   // uniform -> s_load
        a *= 0.25f;
        lg[m] = a; mx = fmaxf(mx, a);
    }
    float s = 0.f;
#pragma unroll
    for (int m = 0; m < 32; m++) { lg[m] = __expf(lg[m] - mx); s += lg[m]; }
    float inv = 1.f / s;      // precise: softmax feeds everything downstream
    float4* wp = (float4*)(wout + (size_t)idx * 32);
#pragma unroll
    for (int m = 0; m < 8; m++)
        wp[m] = make_float4(lg[4 * m] * inv, lg[4 * m + 1] * inv,
                            lg[4 * m + 2] * inv, lg[4 * m + 3] * inv);
}

// ---------------- WtW/WtT partials: 1024 blocks x 128 tokens, no atomics ----------------
__global__ __launch_bounds__(256) void memcell_acc_kern(
    const float* __restrict__ wmat, const __hip_bfloat16* __restrict__ tstar,
    float* __restrict__ part)
{
    __shared__ float ws[64][32];     // 8 KB
    __shared__ float ts[64 * 128];   // 32 KB
    int tid = threadIdx.x;
    int sg = tid & 31, mg = tid >> 5;
    int mW = tid & 31, m2 = (tid >> 5) * 4;
    float accT[16], accW[4];
#pragma unroll
    for (int i = 0; i < 16; i++) accT[i] = 0.f;
#pragma unroll
    for (int i = 0; i < 4; i++) accW[i] = 0.f;

#pragma unroll 1
    for (int cc = 0; cc < 2; cc++) {
        int c = blockIdx.x * 2 + cc;
        size_t base = (size_t)c * 64;
        __syncthreads();
        {
            const float4* src = (const float4*)(wmat + base * 32);
            float4* dst = (float4*)&ws[0][0];
#pragma unroll
            for (int i = 0; i < 2; i++) dst[tid + 256 * i] = src[tid + 256 * i];
            const float4* src2 = (const float4*)(tstar + base * 128);
#pragma unroll
            for (int i = 0; i < 4; i++) {
                union { float4 v; unsigned short us[8]; } u;
                u.v = src2[tid + 256 * i];
                float* d = &ts[(tid + 256 * i) * 8];
                float4 lo = make_float4(bf2f(u.us[0]), bf2f(u.us[1]), bf2f(u.us[2]), bf2f(u.us[3]));
                float4 hi = make_float4(bf2f(u.us[4]), bf2f(u.us[5]), bf2f(u.us[6]), bf2f(u.us[7]));
                *(float4*)d = lo; *(float4*)(d + 4) = hi;
            }
        }
        __syncthreads();
        for (int t = 0; t < 64; t++) {
            float4 wv = *(const float4*)&ws[t][mg * 4];
            float4 sv = *(const float4*)&ts[t * 128 + sg * 4];
            accT[0]  += wv.x * sv.x; accT[1]  += wv.x * sv.y; accT[2]  += wv.x * sv.z; accT[3]  += wv.x * sv.w;
            accT[4]  += wv.y * sv.x; accT[5]  += wv.y * sv.y; accT[6]  += wv.y * sv.z; accT[7]  += wv.y * sv.w;
            accT[8]  += wv.z * sv.x; accT[9]  += wv.z * sv.y; accT[10] += wv.z * sv.z; accT[11] += wv.z * sv.w;
            accT[12] += wv.w * sv.x; accT[13] += wv.w * sv.y; accT[14] += wv.w * sv.z; accT[15] += wv.w * sv.w;
            float wa = ws[t][mW];
            float4 wb = *(const float4*)&ws[t][m2];
            accW[0] += wa * wb.x; accW[1] += wa * wb.y;
            accW[2] += wa * wb.z; accW[3] += wa * wb.w;
        }
    }
    float* pb = part + (size_t)blockIdx.x * 5120;
#pragma unroll
    for (int i = 0; i < 16; i++) pb[i * 256 + tid] = accT[i];
#pragma unroll
    for (int i = 0; i < 4; i++) pb[4096 + i * 256 + tid] = accW[i];
}

// ---------------- reduce 1024 partials -> WtT [32,128], WtW [32,32] ----------------
__global__ __launch_bounds__(256) void memcell_reduce_kern(
    const float* __restrict__ part, float* __restrict__ WtT, float* __restrict__ WtW)
{
    int gid = blockIdx.x * 256 + threadIdx.x;   // 81920
    int j = gid % 5120, seg = gid / 5120;
    const float* p = part + (size_t)seg * 64 * 5120 + j;
    float s = 0.f;
#pragma unroll 8
    for (int k = 0; k < 64; k++) s += p[(size_t)k * 5120];
    int i = j >> 8, t = j & 255;
    if (j < 4096) {
        int sg = t & 31, mg = t >> 5;
        atomicAdd(&WtT[(mg * 4 + (i >> 2)) * 128 + sg * 4 + (i & 3)], s);
    } else {
        int i2 = i - 16;
        int mW = t & 31, m2 = (t >> 5) * 4;
        atomicAdd(&WtW[mW * 32 + m2 + i2], s);
    }
}

// ------- cell_v_new = cell_v + ALPHA*(WtT - WtW @ cell_v)  [32,128] -------
__global__ __launch_bounds__(256) void cvnew_kern(
    const float* __restrict__ cv, const float* __restrict__ WtW,
    const float* __restrict__ WtT, float* __restrict__ cvn)
{
    int idx = blockIdx.x * 256 + threadIdx.x;   // 4096
    int s = idx & 127, m = idx >> 7;
    float g = WtT[idx];
#pragma unroll
    for (int j = 0; j < 32; j++) g -= WtW[m * 32 + j] * cv[j * 128 + s];
    cvn[idx] = cv[idx] + ALPHA_F * g;
}

// ------- E[m][pos*4+co] = sum_ci cvn[m][ci] * dw[ci][co][kh][kw] -------
__global__ __launch_bounds__(256) void emat_kern(
    const float* __restrict__ cvn, const float* __restrict__ dw, float* __restrict__ E)
{
    int idx = blockIdx.x * 256 + threadIdx.x;   // 2048
    int m = idx >> 6, j = idx & 63;
    int pos = j >> 2, co = j & 3;
    float s = 0.f;
    if (co < 3) {
        const float* cv = cvn + m * 128;        // uniform per 64-lane group -> s_loads
        for (int ci = 0; ci < 128; ci++)
            s += cv[ci] * dw[ci * 48 + co * 16 + pos];
    }
    E[idx] = s;
}

// ------- t64[pos][Tglobal][4] = (wmat[T,32] @ E[32,64]) pos-major (coalesced stores) -------
__global__ __launch_bounds__(256) void tread64_kern(
    const float* __restrict__ wmat, const float* __restrict__ E, float* __restrict__ t64)
{
    int t = blockIdx.x * 256 + threadIdx.x;
    float wv[32];
    const float4* wp = (const float4*)(wmat + (size_t)t * 32);
#pragma unroll
    for (int i = 0; i < 8; i++) {
        float4 v = wp[i];
        wv[4 * i] = v.x; wv[4 * i + 1] = v.y; wv[4 * i + 2] = v.z; wv[4 * i + 3] = v.w;
    }
    f32x4 acc[16];
#pragma unroll
    for (int i = 0; i < 16; i++)
#pragma unroll
        for (int r = 0; r < 4; r++) acc[i][r] = 0.f;
    const f32x4* E4 = (const f32x4*)E;
#pragma unroll 4
    for (int m = 0; m < 32; m++) {
        float wm = wv[m];
#pragma unroll
        for (int i = 0; i < 16; i++) {
            f32x4 e = E4[m * 16 + i];           // uniform -> s_load_dwordx4
#pragma unroll
            for (int r = 0; r < 4; r++) acc[i][r] += wm * e[r];
        }
    }
    f32x4* ob = (f32x4*)t64;
#pragma unroll
    for (int i = 0; i < 16; i++)
        ob[(size_t)i * TTOT + t] = acc[i];      // lane-consecutive 16B per pos-plane
}

// ------- decoder gather: dec1 = silu(sum of 4 taps from t64 + bias) -------
__global__ __launch_bounds__(256) void dec_gather_kern(
    const float* __restrict__ t64, const float* __restrict__ db, float* __restrict__ out)
{
    int g = blockIdx.x;                   // 512: b*64 + hb*8 + wb
    int wb = g & 7, hb = (g >> 3) & 7, b = g >> 6;
    int tx = threadIdx.x & 15, ty = threadIdx.x >> 4;
    int h2 = hb * 16 + ty, w2 = wb * 16 + tx;

    float mh[3], mw[3];
    int ihc[3], iwc[3];
#pragma unroll
    for (int a = 0; a < 3; a++) {
        int v = h2 - 1 + a;
        mh[a] = ((unsigned)v < 128u) ? 1.f : 0.f;
        ihc[a] = v < 0 ? 0 : (v > 127 ? 127 : v);
        v = w2 - 1 + a;
        mw[a] = ((unsigned)v < 128u) ? 1.f : 0.f;
        iwc[a] = v < 0 ? 0 : (v > 127 ? 127 : v);
    }
    float acc[2][2][3];
#pragma unroll
    for (int ph = 0; ph < 2; ph++)
#pragma unroll
        for (int pw = 0; pw < 2; pw++)
#pragma unroll
            for (int co = 0; co < 3; co++) acc[ph][pw][co] = db[co];

    const int RA[4] = {0, 1, 1, 2}, RP[4] = {0, 0, 1, 1}, RK[4] = {3, 1, 2, 0};
    size_t tokb = (size_t)b * 16384;
#pragma unroll
    for (int ri = 0; ri < 4; ri++)
#pragma unroll
        for (int cj = 0; cj < 4; cj++) {
            int a = RA[ri], c = RA[cj];
            float m = mh[a] * mw[c];
            size_t tok = tokb + (ihc[a] << 7) + iwc[c];
            int pos = RK[ri] * 4 + RK[cj];
            float4 v = *(const float4*)&t64[((size_t)pos * TTOT + tok) * 4];
            int ph = RP[ri], pw = RP[cj];
            acc[ph][pw][0] += m * v.x;
            acc[ph][pw][1] += m * v.y;
            acc[ph][pw][2] += m * v.z;
        }
    int h = 2 * h2, w = 2 * w2;
#pragma unroll
    for (int ph = 0; ph < 2; ph++)
#pragma unroll
        for (int co = 0; co < 3; co++) {
            float2 v = make_float2(silu_f(acc[ph][0][co]), silu_f(acc[ph][1][co]));
            *(float2*)&out[(size_t)b * 3 * 65536 + (size_t)co * 65536 + ((size_t)(h + ph) << 8) + w] = v;
        }
}

extern "C" void kernel_launch(void* const* d_in, const int* in_sizes, int n_in,
                              void* d_out, int out_size, void* d_ws, size_t ws_size,
                              hipStream_t stream)
{
    const float* x      = (const float*)d_in[0];
    const float* e0n_w1 = (const float*)d_in[1];
    const float* e0n_b1 = (const float*)d_in[2];
    const float* e0n_w2 = (const float*)d_in[3];
    const float* e0n_b2 = (const float*)d_in[4];
    const float* e0s_w1 = (const float*)d_in[5];
    const float* e0s_b1 = (const float*)d_in[6];
    const float* e0s_w2 = (const float*)d_in[7];
    const float* e0s_b2 = (const float*)d_in[8];
    const float* d0_dw  = (const float*)d_in[9];
    const float* d0_db  = (const float*)d_in[10];
    const float* d0_cw  = (const float*)d_in[11];
    const float* d0_cb  = (const float*)d_in[12];
    const float* cell_k = (const float*)d_in[13];
    const float* cell_v = (const float*)d_in[14];
    float* outp = (float*)d_out;

    char* ws = (char*)d_ws;
    char* a_s8             = ws;                              // 67 MB fp8
    __hip_bfloat16* t_star = (__hip_bfloat16*)(ws + 134217728);
    char* wt8     = (char*)(ws + 201326592);
    float* part   = (float*)(ws + 201850880);                 // 21 MB partials
    float* Emat   = (float*)(ws + 224000000);                 // 8 KB
    float* wmat   = (float*)(ws + 243269632);
    float* WtW    = (float*)(ws + 260046848);
    float* WtT    = (float*)(ws + 260050944);
    float* cvn    = (float*)(ws + 260067328);
    float* t64    = (float*)(ws);               // reuse a_s8 region (dead after conv2s)
    float* dec1   = (float*)(ws + 67108864);
    unsigned* xpad = (unsigned*)(ws + 73400320);              // R21: bf16 padded x, 3.37 MB
    unsigned* wbf  = (unsigned*)(ws + 76800000);              // R21: bf16 conv1s weights, 10 KB
    float* wn      = (float*)(ws + 76810240);                 // R24: conv2n weights [9][16][16]
    float* a_nc    = (float*)(ws + 77594624);                 // R24: channels-last n-act, 34.9 MB

    // prep: padded bf16 x + conv1s bf16 weights + conv2n [k][ci][co] weights + a_nc borders
    sprep_kern<<<3552, 256, 0, stream>>>(x, e0s_w1, e0n_w2, xpad, wbf, wn, a_nc);
    // n-branch encoder; conv2n writes wmat directly (softmax fused)
    conv1n_silu<<<2048, 256, 0, stream>>>(x, e0n_w1, e0n_b1, a_nc);
    conv2n_fused<<<512, 256, 0, stream>>>(a_nc, wn, e0n_b2, cell_k, wmat);
    // s-branch encoder: fp8 MFMA conv1 (co-split) -> fp8 MFMA implicit-GEMM conv2
    wprep_kern<<<144, 256, 0, stream>>>(e0s_w2, (int*)wt8);
    conv1s_mfma<<<8192, 256, 0, stream>>>((const unsigned short*)xpad,
                                          (const unsigned short*)wbf, e0s_b1, a_s8);
    conv2s_mfma<<<2048, 256, 0, stream>>>(a_s8, wt8, e0s_b2, t_star);
    // memcell
    hipMemsetAsync(WtW, 0, (1024 + 4096) * sizeof(float), stream);
    memcell_acc_kern<<<1024, 256, 0, stream>>>(wmat, t_star, part);
    memcell_reduce_kern<<<320, 256, 0, stream>>>(part, WtT, WtW);
    cvnew_kern<<<16, 256, 0, stream>>>(cell_v, WtW, WtT, cvn);
    // decoder: fold deconv weights through cvn, then gather from wmat-space (pos-major t64)
    emat_kern<<<8, 256, 0, stream>>>(cvn, d0_dw, Emat);
    tread64_kern<<<512, 256, 0, stream>>>(wmat, Emat, t64);
    dec_gather_kern<<<512, 256, 0, stream>>>(t64, d0_db, dec1);
    conv1_silu<3><<<2048, 256, 0, stream>>>(dec1, d0_cw, d0_cb, outp);
}